// Round 17
// baseline (126.699 us; speedup 1.0000x reference)
//
#include <hip/hip_runtime.h>
#include <hip/hip_bf16.h>

#define NUM_NODES 100000
#define IN_F 256
#define OUT_F 128
#define TILE 128
#define NT ((NUM_NODES + TILE - 1) / TILE)   // 782 tiles of 128 nodes
#define CHUNKD 4096          // edges per split block -> 391 blocks, 1024 thr
#define CAP 2560             // per-tile record capacity (mean 2046, 11 sigma)

typedef __attribute__((ext_vector_type(8))) short bf16x8;
typedef __attribute__((ext_vector_type(4))) float f32x4;

// float -> bf16 (RNE) via HW convert; compiler pairs these into
// v_cvt_pk_bf16_f32 (2 floats/inst) — manual bit-twiddle defeats that.
__device__ inline unsigned short f2bf(float f) {
    __hip_bfloat16 h = __float2bfloat16(f);
    unsigned short u;
    __builtin_memcpy(&u, &h, 2);
    return u;
}
__device__ inline float bf_lo(unsigned int u) { return __uint_as_float(u << 16); }
__device__ inline float bf_hi(unsigned int u) { return __uint_as_float(u & 0xFFFF0000u); }

// ---------------------------------------------------------------------------
// WT[n][k] = bf16(W[k][n])
// ---------------------------------------------------------------------------
__global__ __launch_bounds__(256) void convert_wt_kernel(
    const float* __restrict__ w, unsigned short* __restrict__ wt)
{
    int g = blockIdx.x * 256 + threadIdx.x;      // 0..32767 = k*128+n
    int k = g >> 7, n = g & 127;
    wt[n * 256 + k] = f2bf(w[g]);
}

// ---------------------------------------------------------------------------
// support = bf16(X @ W) via MFMA. 8 waves x 16-row strips = 128 rows/block.
// 2-stage WT staging (34.8 KB LDS -> 4 blocks/CU). A-path converts fp32->
// bf16 with HW cvt (pairs into v_cvt_pk_bf16_f32).
// ---------------------------------------------------------------------------
__global__ __launch_bounds__(512) void gemm_mfma_kernel(
    const float* __restrict__ x, const unsigned short* __restrict__ wt,
    unsigned short* __restrict__ support_h)
{
    __shared__ unsigned short WT[128][136];   // k-half + 8-ushort pad

    const int tid = threadIdx.x;
    const int wave = tid >> 6;
    const int lane = tid & 63;
    const int q = lane >> 4;
    const int r16 = lane & 15;
    const int strip_row = blockIdx.x * 128 + wave * 16;

    int arow = strip_row + r16;
    if (arow >= NUM_NODES) arow = NUM_NODES - 1;
    const float* xrow = x + (size_t)arow * IN_F + q * 8;

    f32x4 acc[8];
#pragma unroll
    for (int n = 0; n < 8; ++n) acc[n] = (f32x4){0.f, 0.f, 0.f, 0.f};

#pragma unroll
    for (int half = 0; half < 2; ++half) {
        __syncthreads();   // protect WT reads of the previous half
        // Stage this k-half of WT: 128 rows x 128 ushorts = 2048 uint4.
#pragma unroll
        for (int i = 0; i < 4; ++i) {
            int j = tid + i * 512;
            int r = j >> 4;                  // 16 uint4 per 128-ushort row
            int c = (j & 15) << 3;           // ushort offset within half
            *reinterpret_cast<uint4*>(&WT[r][c]) =
                *reinterpret_cast<const uint4*>(&wt[r * 256 + half * 128 + c]);
        }
        __syncthreads();

        // Prefetch this half's A (8 float4 in flight).
        float4 a[8];
#pragma unroll
        for (int g = 0; g < 4; ++g) {
            const float* p = xrow + half * 128 + g * 32;
            a[g * 2]     = *reinterpret_cast<const float4*>(p);
            a[g * 2 + 1] = *reinterpret_cast<const float4*>(p + 4);
        }
#pragma unroll
        for (int g = 0; g < 4; ++g) {
            const int k0 = g * 32;           // col within the staged half
            bf16x8 af;
            af[0] = (short)f2bf(a[g * 2].x);
            af[1] = (short)f2bf(a[g * 2].y);
            af[2] = (short)f2bf(a[g * 2].z);
            af[3] = (short)f2bf(a[g * 2].w);
            af[4] = (short)f2bf(a[g * 2 + 1].x);
            af[5] = (short)f2bf(a[g * 2 + 1].y);
            af[6] = (short)f2bf(a[g * 2 + 1].z);
            af[7] = (short)f2bf(a[g * 2 + 1].w);
#pragma unroll
            for (int n = 0; n < 8; ++n) {
                bf16x8 bfr = *reinterpret_cast<const bf16x8*>(
                    &WT[n * 16 + r16][k0 + q * 8]);
                acc[n] = __builtin_amdgcn_mfma_f32_16x16x32_bf16(
                    af, bfr, acc[n], 0, 0, 0);
            }
        }
    }

#pragma unroll
    for (int n = 0; n < 8; ++n) {
#pragma unroll
        for (int rr = 0; rr < 4; ++rr) {
            int grow = strip_row + q * 4 + rr;
            if (grow < NUM_NODES)
                support_h[(size_t)grow * OUT_F + n * 16 + r16] = f2bf(acc[n][rr]);
        }
    }
}

// ---------------------------------------------------------------------------
// Single-pass direct tile split. 1024 threads, 4096 edges/block (391 blocks).
// LDS histogram over 782 buckets, one global atomicAdd per non-empty bucket
// reserves a contiguous range, then direct scattered writes at LDS-ranked
// positions. rec = (row << 7) | (col & 127).  (round-16 verified)
// ---------------------------------------------------------------------------
__global__ __launch_bounds__(1024) void tile_split_direct_kernel(
    const int* __restrict__ ei, int E, int* __restrict__ gcursor,
    unsigned int* __restrict__ brec)
{
    __shared__ int hist[NT];
    __shared__ int cur[NT];
    const int t = threadIdx.x;
    const int e0 = blockIdx.x * CHUNKD;

    for (int i = t; i < NT; i += 1024) hist[i] = 0;
    __syncthreads();

    int colv[4];
#pragma unroll
    for (int i = 0; i < 4; ++i) {
        int e = e0 + i * 1024 + t;
        colv[i] = (e < E) ? ei[E + e] : -1;
        if (colv[i] >= 0) atomicAdd(&hist[colv[i] >> 7], 1);
    }
    __syncthreads();

    for (int b = t; b < NT; b += 1024) {
        int h = hist[b];
        cur[b] = h ? atomicAdd(&gcursor[b], h) : 0;   // global base directly
    }
    __syncthreads();

#pragma unroll
    for (int i = 0; i < 4; ++i) {
        int e = e0 + i * 1024 + t;
        if (colv[i] >= 0) {
            int row = ei[e];
            int b = colv[i] >> 7;
            int pos = atomicAdd(&cur[b], 1);
            if (pos < CAP)
                brec[(size_t)b * CAP + pos] =
                    ((unsigned)row << 7) | (unsigned)(colv[i] & 127);
        }
    }
}

// ---------------------------------------------------------------------------
// Fused per-tile counting-sort + register-accumulate aggregate.
// (round-13 verified verbatim: 8-deep gather batches, VGPR 32, ~68 us)
// ---------------------------------------------------------------------------
__global__ __launch_bounds__(512) void tile_sort_agg_kernel(
    const unsigned int* __restrict__ support_bf,
    const unsigned int* __restrict__ brec,
    const int* __restrict__ gcursor,
    const float* __restrict__ bias,
    float* __restrict__ out)
{
    __shared__ unsigned int recs[CAP];
    __shared__ int srow[CAP];
    __shared__ int hist[128], off[128], cur[128];

    const int tid = threadIdx.x;
    const int lane = tid & 63;
    const int wid = tid >> 6;
    const int node0 = blockIdx.x << 7;

    float accx[16], accy[16];
#pragma unroll
    for (int li = 0; li < 16; ++li) { accx[li] = 0.f; accy[li] = 0.f; }

    int cnt = gcursor[blockIdx.x];
    if (cnt > CAP) cnt = CAP;
    const unsigned int* tb = brec + (size_t)blockIdx.x * CAP;

    if (tid < 128) hist[tid] = 0;
    __syncthreads();

    for (int i = tid; i < cnt; i += 512) {
        unsigned r = tb[i];
        recs[i] = r;
        atomicAdd(&hist[r & 127], 1);
    }
    __syncthreads();

    if (wid == 0) {
        int h0 = hist[2 * lane];
        int h1 = hist[2 * lane + 1];
        int s = h0 + h1;
        int sc = s;
#pragma unroll
        for (int d = 1; d < 64; d <<= 1) {
            int t2 = __shfl_up(sc, d);
            if (lane >= d) sc += t2;
        }
        int ex = sc - s;
        off[2 * lane]     = ex;      cur[2 * lane]     = ex;
        off[2 * lane + 1] = ex + h0; cur[2 * lane + 1] = ex + h0;
    }
    __syncthreads();

    for (int i = tid; i < cnt; i += 512) {
        unsigned r = recs[i];
        int pos = atomicAdd(&cur[r & 127], 1);
        srow[pos] = (int)(r >> 7);
    }
    __syncthreads();

#pragma unroll
    for (int li = 0; li < 16; ++li) {
        const int c = li * 8 + wid;
        int j = off[c];
        const int jend = j + hist[c];
        float ax = accx[li], ay = accy[li];
        for (; j + 7 < jend; j += 8) {
            int r0 = srow[j],     r1 = srow[j + 1];
            int r2 = srow[j + 2], r3 = srow[j + 3];
            int r4 = srow[j + 4], r5 = srow[j + 5];
            int r6 = srow[j + 6], r7 = srow[j + 7];
            unsigned u0 = support_bf[(size_t)r0 * 64 + lane];
            unsigned u1 = support_bf[(size_t)r1 * 64 + lane];
            unsigned u2 = support_bf[(size_t)r2 * 64 + lane];
            unsigned u3 = support_bf[(size_t)r3 * 64 + lane];
            unsigned u4 = support_bf[(size_t)r4 * 64 + lane];
            unsigned u5 = support_bf[(size_t)r5 * 64 + lane];
            unsigned u6 = support_bf[(size_t)r6 * 64 + lane];
            unsigned u7 = support_bf[(size_t)r7 * 64 + lane];
            ax += bf_lo(u0); ay += bf_hi(u0);
            ax += bf_lo(u1); ay += bf_hi(u1);
            ax += bf_lo(u2); ay += bf_hi(u2);
            ax += bf_lo(u3); ay += bf_hi(u3);
            ax += bf_lo(u4); ay += bf_hi(u4);
            ax += bf_lo(u5); ay += bf_hi(u5);
            ax += bf_lo(u6); ay += bf_hi(u6);
            ax += bf_lo(u7); ay += bf_hi(u7);
        }
        for (; j + 3 < jend; j += 4) {
            int r0 = srow[j],     r1 = srow[j + 1];
            int r2 = srow[j + 2], r3 = srow[j + 3];
            unsigned u0 = support_bf[(size_t)r0 * 64 + lane];
            unsigned u1 = support_bf[(size_t)r1 * 64 + lane];
            unsigned u2 = support_bf[(size_t)r2 * 64 + lane];
            unsigned u3 = support_bf[(size_t)r3 * 64 + lane];
            ax += bf_lo(u0); ay += bf_hi(u0);
            ax += bf_lo(u1); ay += bf_hi(u1);
            ax += bf_lo(u2); ay += bf_hi(u2);
            ax += bf_lo(u3); ay += bf_hi(u3);
        }
        for (; j < jend; ++j) {
            unsigned u0 = support_bf[(size_t)srow[j] * 64 + lane];
            ax += bf_lo(u0); ay += bf_hi(u0);
        }
        accx[li] = ax; accy[li] = ay;
    }

    const int nrows = min(TILE, NUM_NODES - node0);
    float2 bi = *reinterpret_cast<const float2*>(bias + lane * 2);
#pragma unroll
    for (int li = 0; li < 16; ++li) {
        const int c = li * 8 + wid;
        if (c < nrows) {
            const int nd = node0 + c;
            unsigned s = support_bf[(size_t)nd * 64 + lane];
            float2 o = {accx[li] + bf_lo(s) + bi.x,
                        accy[li] + bf_hi(s) + bi.y};
            *reinterpret_cast<float2*>(out + (size_t)nd * OUT_F + lane * 2) = o;
        }
    }
}

extern "C" void kernel_launch(void* const* d_in, const int* in_sizes, int n_in,
                              void* d_out, int out_size, void* d_ws, size_t ws_size,
                              hipStream_t stream) {
    const float* x    = (const float*)d_in[0];
    const float* w    = (const float*)d_in[1];
    const float* bias = (const float*)d_in[2];
    const int*   ei   = (const int*)d_in[3];
    float* out = (float*)d_out;
    const int E = in_sizes[3] / 2;
    const int N = NUM_NODES;

    // Workspace layout (~33.7 MB):
    //   support_bf : N*64 uints (bf16x2)   = 25.6 MB
    //   wt_bf      : 128*256 ushorts       = 64 KB
    //   gcursor    : 1024 ints (per tile)
    //   brec       : NT*CAP uints          = 8.0 MB
    unsigned int* support_bf = (unsigned int*)d_ws;
    unsigned short* wt_bf = (unsigned short*)(support_bf + (size_t)N * 64);
    int* gcursor = (int*)(wt_bf + 128 * 256);
    unsigned int* brec = (unsigned int*)(gcursor + 1024);

    // 0. W transpose+convert and cursor clear
    convert_wt_kernel<<<128, 256, 0, stream>>>(w, wt_bf);
    hipMemsetAsync(gcursor, 0, 1024 * sizeof(int), stream);

    // 1. GEMM: support = bf16(X @ W) via MFMA (2-stage WT, HW cvt A-path)
    gemm_mfma_kernel<<<(N + 127) / 128, 512, 0, stream>>>(
        x, wt_bf, (unsigned short*)support_bf);

    // 2. Single-pass direct tile split (1024 thr, 4096 edges/block)
    tile_split_direct_kernel<<<(E + CHUNKD - 1) / CHUNKD, 1024, 0, stream>>>(
        ei, E, gcursor, brec);

    // 3. Fused per-tile sort + register-accumulate aggregate (8-deep MLP)
    tile_sort_agg_kernel<<<NT, 512, 0, stream>>>(
        support_bf, brec, gcursor, bias, out);
}

// Round 18
// 122.218 us; speedup vs baseline: 1.0367x; 1.0367x over previous
//
#include <hip/hip_runtime.h>
#include <hip/hip_bf16.h>

#define NUM_NODES 100000
#define IN_F 256
#define OUT_F 128
#define TILE 128
#define NT ((NUM_NODES + TILE - 1) / TILE)   // 782 tiles of 128 nodes
#define CHUNKD 4096          // edges per split block -> 391 split blocks
#define CAP 2560             // per-tile record capacity (mean 2046, 11 sigma)

typedef __attribute__((ext_vector_type(8))) short bf16x8;
typedef __attribute__((ext_vector_type(4))) float f32x4;

__device__ inline unsigned short f2bf(float f) {
    __hip_bfloat16 h = __float2bfloat16(f);
    unsigned short u;
    __builtin_memcpy(&u, &h, 2);
    return u;
}
__device__ inline float bf_lo(unsigned int u) { return __uint_as_float(u << 16); }
__device__ inline float bf_hi(unsigned int u) { return __uint_as_float(u & 0xFFFF0000u); }

// ---------------------------------------------------------------------------
// WT[n][k] = bf16(W[k][n])
// ---------------------------------------------------------------------------
__global__ __launch_bounds__(256) void convert_wt_kernel(
    const float* __restrict__ w, unsigned short* __restrict__ wt)
{
    int g = blockIdx.x * 256 + threadIdx.x;      // 0..32767 = k*128+n
    int k = g >> 7, n = g & 127;
    wt[n * 256 + k] = f2bf(w[g]);
}

// ---------------------------------------------------------------------------
// Fused GEMM + split, role-interleaved trios [gemm, gemm, split].
// gemm role: 2-stage WT (34.8 KB LDS) MFMA, 8 waves x 16-row strips.
// split role: direct tile split, 4096 edges, LDS hist (6.3 KB logical).
// LDS union = 34.8 KB -> 3-4 blocks/CU, so the latency-bound split truly
// co-resides with the load/MFMA-bound gemm (round-11 failed at 67.6 KB).
// ---------------------------------------------------------------------------
union ShmFused {
    unsigned short WT[128][136];                 // 34816 B
    struct { int hist[NT]; int cur[NT]; } sp;    //  6256 B
};

__global__ __launch_bounds__(512) void gemm_split_kernel(
    const float* __restrict__ x, const unsigned short* __restrict__ wt,
    unsigned short* __restrict__ support_h,
    const int* __restrict__ ei, int E,
    int* __restrict__ gcursor, unsigned int* __restrict__ brec)
{
    __shared__ ShmFused shm;
    const int tid = threadIdx.x;
    const int trio = blockIdx.x / 3;
    const int pos = blockIdx.x % 3;

    if (pos < 2) {
        // ----------------- GEMM tile (128 rows) -----------------
        const int idx = trio * 2 + pos;
        const int wave = tid >> 6;
        const int lane = tid & 63;
        const int q = lane >> 4;
        const int r16 = lane & 15;
        const int strip_row = idx * 128 + wave * 16;

        int arow = strip_row + r16;
        if (arow >= NUM_NODES) arow = NUM_NODES - 1;
        const float* xrow = x + (size_t)arow * IN_F + q * 8;

        f32x4 acc[8];
#pragma unroll
        for (int n = 0; n < 8; ++n) acc[n] = (f32x4){0.f, 0.f, 0.f, 0.f};

#pragma unroll
        for (int half = 0; half < 2; ++half) {
            __syncthreads();
#pragma unroll
            for (int i = 0; i < 4; ++i) {
                int j = tid + i * 512;
                int r = j >> 4;
                int c = (j & 15) << 3;
                *reinterpret_cast<uint4*>(&shm.WT[r][c]) =
                    *reinterpret_cast<const uint4*>(
                        &wt[r * 256 + half * 128 + c]);
            }
            __syncthreads();

            float4 a[8];
#pragma unroll
            for (int g = 0; g < 4; ++g) {
                const float* p = xrow + half * 128 + g * 32;
                a[g * 2]     = *reinterpret_cast<const float4*>(p);
                a[g * 2 + 1] = *reinterpret_cast<const float4*>(p + 4);
            }
#pragma unroll
            for (int g = 0; g < 4; ++g) {
                const int k0 = g * 32;
                bf16x8 af;
                af[0] = (short)f2bf(a[g * 2].x);
                af[1] = (short)f2bf(a[g * 2].y);
                af[2] = (short)f2bf(a[g * 2].z);
                af[3] = (short)f2bf(a[g * 2].w);
                af[4] = (short)f2bf(a[g * 2 + 1].x);
                af[5] = (short)f2bf(a[g * 2 + 1].y);
                af[6] = (short)f2bf(a[g * 2 + 1].z);
                af[7] = (short)f2bf(a[g * 2 + 1].w);
#pragma unroll
                for (int n = 0; n < 8; ++n) {
                    bf16x8 bfr = *reinterpret_cast<const bf16x8*>(
                        &shm.WT[n * 16 + r16][k0 + q * 8]);
                    acc[n] = __builtin_amdgcn_mfma_f32_16x16x32_bf16(
                        af, bfr, acc[n], 0, 0, 0);
                }
            }
        }

#pragma unroll
        for (int n = 0; n < 8; ++n) {
#pragma unroll
            for (int rr = 0; rr < 4; ++rr) {
                int grow = strip_row + q * 4 + rr;
                if (grow < NUM_NODES)
                    support_h[(size_t)grow * OUT_F + n * 16 + r16] =
                        f2bf(acc[n][rr]);
            }
        }
    } else {
        // ----------------- direct tile split (4096 edges) -----------------
        const int e0 = trio * CHUNKD;

        for (int i = tid; i < NT; i += 512) shm.sp.hist[i] = 0;
        __syncthreads();

        int colv[8];
#pragma unroll
        for (int i = 0; i < 8; ++i) {
            int e = e0 + i * 512 + tid;
            colv[i] = (e < E) ? ei[E + e] : -1;
            if (colv[i] >= 0) atomicAdd(&shm.sp.hist[colv[i] >> 7], 1);
        }
        __syncthreads();

        for (int b = tid; b < NT; b += 512) {
            int h = shm.sp.hist[b];
            shm.sp.cur[b] = h ? atomicAdd(&gcursor[b], h) : 0;
        }
        __syncthreads();

#pragma unroll
        for (int i = 0; i < 8; ++i) {
            int e = e0 + i * 512 + tid;
            if (colv[i] >= 0) {
                int row = ei[e];
                int b = colv[i] >> 7;
                int p = atomicAdd(&shm.sp.cur[b], 1);
                if (p < CAP)
                    brec[(size_t)b * CAP + p] =
                        ((unsigned)row << 7) | (unsigned)(colv[i] & 127);
            }
        }
    }
}

// ---------------------------------------------------------------------------
// Fused per-tile counting-sort + register-accumulate aggregate.
// (round-13 verified verbatim: 8-deep gather batches, VGPR 32, ~68 us)
// ---------------------------------------------------------------------------
__global__ __launch_bounds__(512) void tile_sort_agg_kernel(
    const unsigned int* __restrict__ support_bf,
    const unsigned int* __restrict__ brec,
    const int* __restrict__ gcursor,
    const float* __restrict__ bias,
    float* __restrict__ out)
{
    __shared__ unsigned int recs[CAP];
    __shared__ int srow[CAP];
    __shared__ int hist[128], off[128], cur[128];

    const int tid = threadIdx.x;
    const int lane = tid & 63;
    const int wid = tid >> 6;
    const int node0 = blockIdx.x << 7;

    float accx[16], accy[16];
#pragma unroll
    for (int li = 0; li < 16; ++li) { accx[li] = 0.f; accy[li] = 0.f; }

    int cnt = gcursor[blockIdx.x];
    if (cnt > CAP) cnt = CAP;
    const unsigned int* tb = brec + (size_t)blockIdx.x * CAP;

    if (tid < 128) hist[tid] = 0;
    __syncthreads();

    for (int i = tid; i < cnt; i += 512) {
        unsigned r = tb[i];
        recs[i] = r;
        atomicAdd(&hist[r & 127], 1);
    }
    __syncthreads();

    if (wid == 0) {
        int h0 = hist[2 * lane];
        int h1 = hist[2 * lane + 1];
        int s = h0 + h1;
        int sc = s;
#pragma unroll
        for (int d = 1; d < 64; d <<= 1) {
            int t2 = __shfl_up(sc, d);
            if (lane >= d) sc += t2;
        }
        int ex = sc - s;
        off[2 * lane]     = ex;      cur[2 * lane]     = ex;
        off[2 * lane + 1] = ex + h0; cur[2 * lane + 1] = ex + h0;
    }
    __syncthreads();

    for (int i = tid; i < cnt; i += 512) {
        unsigned r = recs[i];
        int pos = atomicAdd(&cur[r & 127], 1);
        srow[pos] = (int)(r >> 7);
    }
    __syncthreads();

#pragma unroll
    for (int li = 0; li < 16; ++li) {
        const int c = li * 8 + wid;
        int j = off[c];
        const int jend = j + hist[c];
        float ax = accx[li], ay = accy[li];
        for (; j + 7 < jend; j += 8) {
            int r0 = srow[j],     r1 = srow[j + 1];
            int r2 = srow[j + 2], r3 = srow[j + 3];
            int r4 = srow[j + 4], r5 = srow[j + 5];
            int r6 = srow[j + 6], r7 = srow[j + 7];
            unsigned u0 = support_bf[(size_t)r0 * 64 + lane];
            unsigned u1 = support_bf[(size_t)r1 * 64 + lane];
            unsigned u2 = support_bf[(size_t)r2 * 64 + lane];
            unsigned u3 = support_bf[(size_t)r3 * 64 + lane];
            unsigned u4 = support_bf[(size_t)r4 * 64 + lane];
            unsigned u5 = support_bf[(size_t)r5 * 64 + lane];
            unsigned u6 = support_bf[(size_t)r6 * 64 + lane];
            unsigned u7 = support_bf[(size_t)r7 * 64 + lane];
            ax += bf_lo(u0); ay += bf_hi(u0);
            ax += bf_lo(u1); ay += bf_hi(u1);
            ax += bf_lo(u2); ay += bf_hi(u2);
            ax += bf_lo(u3); ay += bf_hi(u3);
            ax += bf_lo(u4); ay += bf_hi(u4);
            ax += bf_lo(u5); ay += bf_hi(u5);
            ax += bf_lo(u6); ay += bf_hi(u6);
            ax += bf_lo(u7); ay += bf_hi(u7);
        }
        for (; j + 3 < jend; j += 4) {
            int r0 = srow[j],     r1 = srow[j + 1];
            int r2 = srow[j + 2], r3 = srow[j + 3];
            unsigned u0 = support_bf[(size_t)r0 * 64 + lane];
            unsigned u1 = support_bf[(size_t)r1 * 64 + lane];
            unsigned u2 = support_bf[(size_t)r2 * 64 + lane];
            unsigned u3 = support_bf[(size_t)r3 * 64 + lane];
            ax += bf_lo(u0); ay += bf_hi(u0);
            ax += bf_lo(u1); ay += bf_hi(u1);
            ax += bf_lo(u2); ay += bf_hi(u2);
            ax += bf_lo(u3); ay += bf_hi(u3);
        }
        for (; j < jend; ++j) {
            unsigned u0 = support_bf[(size_t)srow[j] * 64 + lane];
            ax += bf_lo(u0); ay += bf_hi(u0);
        }
        accx[li] = ax; accy[li] = ay;
    }

    const int nrows = min(TILE, NUM_NODES - node0);
    float2 bi = *reinterpret_cast<const float2*>(bias + lane * 2);
#pragma unroll
    for (int li = 0; li < 16; ++li) {
        const int c = li * 8 + wid;
        if (c < nrows) {
            const int nd = node0 + c;
            unsigned s = support_bf[(size_t)nd * 64 + lane];
            float2 o = {accx[li] + bf_lo(s) + bi.x,
                        accy[li] + bf_hi(s) + bi.y};
            *reinterpret_cast<float2*>(out + (size_t)nd * OUT_F + lane * 2) = o;
        }
    }
}

extern "C" void kernel_launch(void* const* d_in, const int* in_sizes, int n_in,
                              void* d_out, int out_size, void* d_ws, size_t ws_size,
                              hipStream_t stream) {
    const float* x    = (const float*)d_in[0];
    const float* w    = (const float*)d_in[1];
    const float* bias = (const float*)d_in[2];
    const int*   ei   = (const int*)d_in[3];
    float* out = (float*)d_out;
    const int E = in_sizes[3] / 2;
    const int N = NUM_NODES;

    // Workspace layout (~33.7 MB):
    //   support_bf : N*64 uints (bf16x2)   = 25.6 MB
    //   wt_bf      : 128*256 ushorts       = 64 KB
    //   gcursor    : 1024 ints (per tile)
    //   brec       : NT*CAP uints          = 8.0 MB
    unsigned int* support_bf = (unsigned int*)d_ws;
    unsigned short* wt_bf = (unsigned short*)(support_bf + (size_t)N * 64);
    int* gcursor = (int*)(wt_bf + 128 * 256);
    unsigned int* brec = (unsigned int*)(gcursor + 1024);

    // 0. W transpose+convert and cursor clear
    convert_wt_kernel<<<128, 256, 0, stream>>>(w, wt_bf);
    hipMemsetAsync(gcursor, 0, 1024 * sizeof(int), stream);

    // 1. Fused GEMM + split (trios [gemm, gemm, split]; 3-4 blocks/CU)
    const int nS = (E + CHUNKD - 1) / CHUNKD;    // 391
    gemm_split_kernel<<<nS * 3, 512, 0, stream>>>(
        x, wt_bf, (unsigned short*)support_bf, ei, E, gcursor, brec);

    // 2. Fused per-tile sort + register-accumulate aggregate (8-deep MLP)
    tile_sort_agg_kernel<<<NT, 512, 0, stream>>>(
        support_bf, brec, gcursor, bias, out);
}